// Round 15
// baseline (396.979 us; speedup 1.0000x reference)
//
#include <hip/hip_runtime.h>
#include <hip/hip_bf16.h>
#include <math.h>

#define DIM   384
#define HEADS 12
#define HD    32
#define WIN   7
#define NPIX  49
#define IMG   56
#define NPF   3136   // IMG*IMG
#define NWIN  1024

typedef __attribute__((ext_vector_type(8))) short short8;
typedef __attribute__((ext_vector_type(4))) float f32x4;
typedef __attribute__((ext_vector_type(4))) float f4;
typedef __attribute__((ext_vector_type(4))) unsigned short us4;
typedef __attribute__((ext_vector_type(8))) unsigned short us8;
#define MFMA __builtin_amdgcn_mfma_f32_16x16x32_bf16

__device__ inline ushort tob(float f) {
  unsigned u; __builtin_memcpy(&u, &f, 4);
  u += 0x7fffu + ((u >> 16) & 1u);
  return (ushort)(u >> 16);
}

// ---------------- bias table ----------------
__global__ void k_bias(const float* __restrict__ cpb, float* __restrict__ bias) {
  int idx = blockIdx.x * 256 + threadIdx.x;
  if (idx >= HEADS * NPIX * NPIX) return;
  int m = idx % NPIX;
  int n = (idx / NPIX) % NPIX;
  int h = idx / (NPIX * NPIX);
  int sy = (n / WIN - m / WIN) + (WIN - 1);
  int sx = (n % WIN - m % WIN) + (WIN - 1);
  const double inv_log_beta = 1.0 / log(1.3);
  double fy = (sy == 0 ? 0.0 : log1p((double)sy) * inv_log_beta) + 6.0;
  double fx = (sx == 0 ? 0.0 : log1p((double)sx) * inv_log_beta) + 6.0;
  fy = fmin(12.0, fmax(0.0, fy));
  fx = fmin(12.0, fmax(0.0, fx));
  int ridx = (int)(fy * 13.0 + fx);
  bias[idx] = cpb[ridx * HEADS + h];
}

__global__ void k_rmap(int* __restrict__ rmap) {
  int p = blockIdx.x * 256 + threadIdx.x;
  if (p < NPF) {
    int wb = p / NPIX, n = p - (p / NPIX) * NPIX;
    int gy = wb >> 3, gx = wb & 7;
    int wy = n / WIN, wx = n - (n / WIN) * WIN;
    rmap[p] = ((gy * WIN + wy + 4) % IMG) * IMG + (gx * WIN + wx + 4) % IMG;
  }
}

// ---------------- weights -> bf16 (once) ----------------
__global__ void k_wcvt(const float* __restrict__ wqkv, const float* __restrict__ wproj,
                       ushort* __restrict__ wqb, ushort* __restrict__ wpb) {
  int i = blockIdx.x * 256 + threadIdx.x;
  const int nq = 1152 * DIM / 8;
  const int np = DIM * DIM / 8;
  if (i < nq) {
    f4 a = *(const f4*)&wqkv[i * 8];
    f4 b = *(const f4*)&wqkv[i * 8 + 4];
    us8 u; u[0]=tob(a[0]);u[1]=tob(a[1]);u[2]=tob(a[2]);u[3]=tob(a[3]);
    u[4]=tob(b[0]);u[5]=tob(b[1]);u[6]=tob(b[2]);u[7]=tob(b[3]);
    *(us8*)&wqb[i * 8] = u;
  } else if (i < nq + np) {
    int j = i - nq;
    f4 a = *(const f4*)&wproj[j * 8];
    f4 b = *(const f4*)&wproj[j * 8 + 4];
    us8 u; u[0]=tob(a[0]);u[1]=tob(a[1]);u[2]=tob(a[2]);u[3]=tob(a[3]);
    u[4]=tob(b[0]);u[5]=tob(b[1]);u[6]=tob(b[2]);u[7]=tob(b[3]);
    *(us8*)&wpb[j * 8] = u;
  }
}

// ---------------- x -> xw[b][p'][c] bf16, window-ordered, roll folded -------
__global__ __launch_bounds__(256) void k_xw(const float* __restrict__ x,
                                            const int* __restrict__ rmap,
                                            ushort* __restrict__ xw) {
  int gid = blockIdx.x * 256 + threadIdx.x;   // 16*3136 exact
  int b = gid / NPF, p = gid - (gid / NPF) * NPF;
  int sp = rmap[p];
  const float* xs = x + (size_t)b * DIM * NPF + sp;
  ushort* xd = xw + ((size_t)b * NPF + p) * DIM;
  for (int c0 = 0; c0 < DIM; c0 += 8) {
    us8 u;
#pragma unroll
    for (int i = 0; i < 8; ++i) u[i] = tob(xs[(size_t)(c0 + i) * NPF]);
    *(us8*)&xd[c0] = u;
  }
}

// ---------------- QKV GEMM: no LDS, fragments direct from L2 ----------------
// qkv_pm[b][p'][o] = W . Xw — block 128(o) x 256(p), 4 waves of 64x128.
// grid 1872 = 9 x 13 x 16, XCD-swizzled, o fastest.
__global__ __launch_bounds__(256) void k_qkv_pm(const ushort* __restrict__ xw,
                                                const ushort* __restrict__ wqb,
                                                ushort* __restrict__ qkv) {
  int t   = threadIdx.x;
  int bid = blockIdx.x;
  int swz = (bid & 7) * 234 + (bid >> 3);   // 1872 = 8*234, bijective
  int o0  = (swz % 9) * 128;
  int pbt = swz / 9;
  int p0  = (pbt % 13) * 256;
  int b   = pbt / 13;

  int lane = t & 63, wv = t >> 6;
  int wm = wv >> 1, wn = wv & 1;
  int l15 = lane & 15, l4 = lane >> 4;

  const ushort* aBase[4];
#pragma unroll
  for (int mi = 0; mi < 4; ++mi) {
    int ro = o0 + wm * 64 + mi * 16 + l15;
    aBase[mi] = wqb + (size_t)ro * DIM + l4 * 8;
  }
  const ushort* bBase[8];
#pragma unroll
  for (int ni = 0; ni < 8; ++ni) {
    int p = p0 + wn * 128 + ni * 16 + l15;
    if (p >= NPF) p = NPF - 1;
    bBase[ni] = xw + ((size_t)b * NPF + p) * DIM + l4 * 8;
  }

  f32x4 acc[4][8] = {};
#pragma unroll
  for (int ks = 0; ks < 12; ++ks) {
    short8 af[4], bfr[8];
#pragma unroll
    for (int mi = 0; mi < 4; ++mi) af[mi] = *(const short8*)(aBase[mi] + ks * 32);
#pragma unroll
    for (int ni = 0; ni < 8; ++ni) bfr[ni] = *(const short8*)(bBase[ni] + ks * 32);
#pragma unroll
    for (int mi = 0; mi < 4; ++mi)
#pragma unroll
      for (int ni = 0; ni < 8; ++ni)
        acc[mi][ni] = MFMA(af[mi], bfr[ni], acc[mi][ni], 0, 0, 0);
  }

#pragma unroll
  for (int mi = 0; mi < 4; ++mi)
#pragma unroll
    for (int ni = 0; ni < 8; ++ni) {
      int p = p0 + wn * 128 + ni * 16 + l15;
      if (p < NPF) {
        us4 u;
#pragma unroll
        for (int r = 0; r < 4; ++r) u[r] = tob(acc[mi][ni][r]);
        *(us4*)&qkv[((size_t)b * NPF + p) * 1152 + o0 + wm * 64 + mi * 16 + (l4 << 2)] = u;
      }
    }
}

// ---------------- attention: Q/K frags direct from L2; V via slim LDS -------
__global__ __launch_bounds__(64) void k_attn_pm(ushort* __restrict__ qkv,
                                                const float* __restrict__ bias) {
  __shared__ __align__(16) ushort smem[6912];   // 13824 B
  ushort* svt = smem;          // [32][72] V^T
  ushort* stg = smem + 2304;   // [49][32] staging (overlays pa; dead before pa)
  ushort* pa  = smem + 2304;   // [64][72] P bf16

  int t = threadIdx.x;
  int bid = blockIdx.x;
  int swz = (bid & 7) * 1536 + (bid >> 3);   // 12288 = 8*1536
  int h = swz % HEADS, wb = swz / HEADS;
  int b = wb >> 6;
  int w49 = (wb & 63) * NPIX;
  ushort* qrow = qkv + ((size_t)b * NPF + w49) * 1152 + h * HD;

  // zero svt pad cols 49..71
  for (int idx = t; idx < 32 * 23; idx += 64) {
    int d = idx / 23, mm = 49 + (idx - (idx / 23) * 23);
    svt[d * 72 + mm] = 0;
  }
  // stage V rows [m][d]
  for (int idx = t; idx < NPIX * 4; idx += 64) {
    int n = idx >> 2, s = (idx & 3) * 8;
    *(us8*)&stg[n * 32 + s] = *(const us8*)&qrow[(size_t)n * 1152 + 2 * DIM + s];
  }
  __syncthreads();
  // transpose V -> svt
  for (int idx = t; idx < HD * NPIX; idx += 64) {
    int d = idx / NPIX, m = idx - d * NPIX;
    svt[d * 72 + m] = stg[m * 32 + d];
  }

  // Q/K fragments straight from global (rows clamped; dup rows masked later)
  int l15 = t & 15, l4 = t >> 4;
  short8 af[4], bfr[4];
#pragma unroll
  for (int mi = 0; mi < 4; ++mi) {
    int rq = mi * 16 + l15; if (rq > 48) rq = 48;
    af[mi] = *(const short8*)&qrow[(size_t)rq * 1152 + l4 * 8];
  }
#pragma unroll
  for (int ni = 0; ni < 4; ++ni) {
    int rk = ni * 16 + l15; if (rk > 48) rk = 48;
    bfr[ni] = *(const short8*)&qrow[(size_t)rk * 1152 + DIM + l4 * 8];
  }
  f32x4 acc[4][4] = {};
#pragma unroll
  for (int mi = 0; mi < 4; ++mi)
#pragma unroll
    for (int ni = 0; ni < 4; ++ni)
      acc[mi][ni] = MFMA(af[mi], bfr[ni], acc[mi][ni], 0, 0, 0);

  const float scale = 0.17677669529663687f;
  const float* bh = bias + h * NPIX * NPIX;
  float mx[16], sm[16];
#pragma unroll
  for (int mi = 0; mi < 4; ++mi)
#pragma unroll
    for (int r = 0; r < 4; ++r) {
      int n = mi * 16 + (l4 << 2) + r;
      float vmax = -3e38f;
#pragma unroll
      for (int ni = 0; ni < 4; ++ni) {
        int m = ni * 16 + l15;
        float s = (m < NPIX)
                    ? acc[mi][ni][r] * scale + ((n < NPIX) ? bh[n * NPIX + m] : 0.f)
                    : -3e38f;
        acc[mi][ni][r] = s;
        vmax = fmaxf(vmax, s);
      }
      mx[mi * 4 + r] = vmax;
    }
#pragma unroll
  for (int i = 1; i < 16; i <<= 1)
#pragma unroll
    for (int j = 0; j < 16; ++j) mx[j] = fmaxf(mx[j], __shfl_xor(mx[j], i));
#pragma unroll
  for (int mi = 0; mi < 4; ++mi)
#pragma unroll
    for (int r = 0; r < 4; ++r) {
      float s = 0.f;
#pragma unroll
      for (int ni = 0; ni < 4; ++ni) {
        float e = expf(acc[mi][ni][r] - mx[mi * 4 + r]);
        acc[mi][ni][r] = e;
        s += e;
      }
      sm[mi * 4 + r] = s;
    }
#pragma unroll
  for (int i = 1; i < 16; i <<= 1)
#pragma unroll
    for (int j = 0; j < 16; ++j) sm[j] += __shfl_xor(sm[j], i);

  __syncthreads();   // stg reads done (transpose) -> pa may overwrite
#pragma unroll
  for (int mi = 0; mi < 4; ++mi)
#pragma unroll
    for (int r = 0; r < 4; ++r) {
      float ri = 1.f / sm[mi * 4 + r];
      int n = mi * 16 + (l4 << 2) + r;
#pragma unroll
      for (int ni = 0; ni < 4; ++ni)
        pa[n * 72 + ni * 16 + l15] = tob(acc[mi][ni][r] * ri);
    }
  __syncthreads();

  f32x4 yac[4][2] = {};
#pragma unroll
  for (int ks = 0; ks < 2; ++ks) {
    short8 pf[4], vf[2];
#pragma unroll
    for (int mi = 0; mi < 4; ++mi) pf[mi] = *(const short8*)&pa [(mi * 16 + l15) * 72 + ks * 32 + l4 * 8];
#pragma unroll
    for (int nd = 0; nd < 2; ++nd) vf[nd] = *(const short8*)&svt[(nd * 16 + l15) * 72 + ks * 32 + l4 * 8];
#pragma unroll
    for (int mi = 0; mi < 4; ++mi)
#pragma unroll
      for (int nd = 0; nd < 2; ++nd)
        yac[mi][nd] = MFMA(pf[mi], vf[nd], yac[mi][nd], 0, 0, 0);
  }
  // Y over own Q slice — disjoint across blocks
#pragma unroll
  for (int mi = 0; mi < 4; ++mi)
#pragma unroll
    for (int nd = 0; nd < 2; ++nd) {
      int nb = mi * 16 + (l4 << 2);
      int d = nd * 16 + l15;
#pragma unroll
      for (int r = 0; r < 4; ++r)
        if (nb + r < NPIX) qrow[(size_t)(nb + r) * 1152 + d] = tob(yac[mi][nd][r]);
    }
}

// ---------------- proj GEMM: no LDS (srm table only), frags from L2 ---------
// out[b][o][p] = Wp . Y — block 128(o) x 256(p), 4 waves of 64x128.
// grid 624 = 3 x 13 x 16, XCD-swizzled, o fastest.
__global__ __launch_bounds__(256) void k_proj_pm(const ushort* __restrict__ qkv,
                                                 const ushort* __restrict__ wpb,
                                                 float* __restrict__ out) {
  __shared__ int srm[256];
  int t   = threadIdx.x;
  int bid = blockIdx.x;
  int swz = (bid & 7) * 78 + (bid >> 3);    // 624 = 8*78, bijective
  int o0  = (swz % 3) * 128;
  int pbt = swz / 3;
  int p0  = (pbt % 13) * 256;
  int b   = pbt / 13;
  {
    int pg = p0 + t;
    if (pg >= NPF) pg = 0;
    int si = (pg / IMG + 53) % IMG, sj = (pg % IMG + 53) % IMG;  // inverse roll +3
    srm[t] = ((si / WIN) * 8 + sj / WIN) * NPIX + (si % WIN) * WIN + (sj % WIN);
  }
  __syncthreads();

  int lane = t & 63, wv = t >> 6;
  int wm = wv >> 1, wn = wv & 1;
  int l15 = lane & 15, l4 = lane >> 4;

  const ushort* aBase[4];
#pragma unroll
  for (int mi = 0; mi < 4; ++mi) {
    int ro = o0 + wm * 64 + mi * 16 + l15;
    aBase[mi] = wpb + (size_t)ro * DIM + l4 * 8;
  }
  const ushort* bBase[8];
#pragma unroll
  for (int ni = 0; ni < 8; ++ni) {
    int pr = srm[wn * 128 + ni * 16 + l15];
    bBase[ni] = qkv + ((size_t)b * NPF + pr) * 1152 + l4 * 8;
  }

  f32x4 acc[4][8] = {};
#pragma unroll
  for (int ks = 0; ks < 12; ++ks) {
    short8 af[4], bfr[8];
#pragma unroll
    for (int mi = 0; mi < 4; ++mi) af[mi] = *(const short8*)(aBase[mi] + ks * 32);
#pragma unroll
    for (int ni = 0; ni < 8; ++ni) bfr[ni] = *(const short8*)(bBase[ni] + ks * 32);
#pragma unroll
    for (int mi = 0; mi < 4; ++mi)
#pragma unroll
      for (int ni = 0; ni < 8; ++ni)
        acc[mi][ni] = MFMA(af[mi], bfr[ni], acc[mi][ni], 0, 0, 0);
  }

#pragma unroll
  for (int mi = 0; mi < 4; ++mi)
#pragma unroll
    for (int ni = 0; ni < 8; ++ni) {
      int p = p0 + wn * 128 + ni * 16 + l15;
      if (p < NPF) {
#pragma unroll
        for (int r = 0; r < 4; ++r) {
          int o = o0 + wm * 64 + mi * 16 + (l4 << 2) + r;
          out[((size_t)b * DIM + o) * NPF + p] = acc[mi][ni][r];
        }
      }
    }
}

extern "C" void kernel_launch(void* const* d_in, const int* in_sizes, int n_in,
                              void* d_out, int out_size, void* d_ws, size_t ws_size,
                              hipStream_t stream) {
  const float* x     = (const float*)d_in[0];
  const float* wqkv  = (const float*)d_in[1];
  const float* wproj = (const float*)d_in[2];
  const float* cpb   = (const float*)d_in[3];
  float* out = (float*)d_out;

  char* ws = (char*)d_ws;
  float* bias = (float*)ws;                    // 115248 B
  int*   rmap = (int*)(ws + 115712);           // -> 131072

  const size_t QKV_B = (size_t)16 * 1152 * NPF * 2;       // 115.6 MB
  ushort* wqb = (ushort*)(ws + 131072);                   // 884736 B
  ushort* wpb = (ushort*)(ws + 1015808);                  // 294912 B -> 1310720
  ushort* qkv = (ushort*)(ws + 1310720);
  ushort* xw  = (ushort*)(ws + 1310720 + QKV_B);          // 38.5 MB (ws >= 155.5 MB proven r11-13)

  hipLaunchKernelGGL(k_bias, dim3(113), dim3(256), 0, stream, cpb, bias);
  hipLaunchKernelGGL(k_rmap, dim3(13), dim3(256), 0, stream, rmap);
  hipLaunchKernelGGL(k_wcvt, dim3(288), dim3(256), 0, stream, wqkv, wproj, wqb, wpb);
  hipLaunchKernelGGL(k_xw, dim3(196), dim3(256), 0, stream, x, rmap, xw);
  hipLaunchKernelGGL(k_qkv_pm, dim3(1872), dim3(256), 0, stream, xw, wqb, qkv);
  hipLaunchKernelGGL(k_attn_pm, dim3(NWIN * HEADS), dim3(64), 0, stream, qkv, bias);
  hipLaunchKernelGGL(k_proj_pm, dim3(624), dim3(256), 0, stream, qkv, wpb, out);
}